// Round 1
// baseline (433.528 us; speedup 1.0000x reference)
//
#include <hip/hip_runtime.h>
#include <math.h>

// z:  (2,1,256,256,64)  idx = b*4194304 + x*16384 + y*64 + k
// tg: (2,3,256,256,64)  idx = b*12582912 + c*4194304 + x*16384 + y*64 + k
//
// Tiled stencil: block = 4x4 cells (x0..x0+3, y0..y0+3), full k (64).
// LDS: z strips x0-1..x0+4 (6) x rows y0-1..y0+4 (6) ONLY.
// b fields (targets) are read directly from global in the div phase:
//   each b value is consumed by <=4 cells, reads are wave-coalesced, and
//   L1/L2 serve the reuse -- the LDS round-trip bought nothing and cost
//   19.4KB LDS/block (occupancy) + 24 conflicted ds_read_b128 per thread.
//
// ws layout (floats), 32 slices x 258:
//   sl[p*258 + 0]=smooth, +1=div, +2+b*64+k = s1, +130+b*64+k = s2

#define ZSTR 388            // 6*64 + 4 pad

__global__ __launch_bounds__(512) void zero_ws_kernel(float* ws) {
    for (int i = threadIdx.x; i < 32 * 258; i += 512) ws[i] = 0.0f;
}

// LDS 5-float load (pad region makes the +4 overread safe)
#define LD5(arr, p) do { \
    float4 _a = *(const float4*)(p); float4 _b = *(const float4*)((p) + 4); \
    arr[0] = _a.x; arr[1] = _a.y; arr[2] = _a.z; arr[3] = _a.w; arr[4] = _b.x; } while (0)

// Global 5-float load: float4 + guarded scalar. For kq==15 the 5th element
// is never used (all consumers are masked by k0+e<63 => e<=2), so read a
// safe in-bounds dummy (offset t4=0) instead of crossing the row/array end.
#define LDG5(arr, p) do { \
    float4 _a = *(const float4*)(p); \
    arr[0] = _a.x; arr[1] = _a.y; arr[2] = _a.z; arr[3] = _a.w; \
    arr[4] = (p)[t4]; } while (0)

__global__ __launch_bounds__(256, 5) void fused_loss_kernel(
    const float* __restrict__ zin, const float* __restrict__ tg,
    float* __restrict__ ws)
{
    __shared__ float zs[6 * ZSTR];       // 2328 floats = 9312 B
    __shared__ float rsc[4][2];

    const int tid  = threadIdx.x;
    const int lane = tid & 63;
    const int w    = tid >> 6;

    const int bb = blockIdx.x >> 12;
    const int rest = blockIdx.x & 4095;
    const int x0 = ((rest >> 6) & 63) << 2;
    const int y0 = (rest & 63) << 2;

    const float* zg = zin + ((size_t)bb << 22);

    // ---- cooperative staging: 576 z float4s ----
    for (int i = tid; i < 576; i += 256) {
        int row = i >> 4;
        int o   = (i & 15) << 2;
        int xi  = row / 6;
        int yr  = row - xi * 6;
        int x = x0 - 1 + xi; x = x < 0 ? 0 : (x > 255 ? 255 : x);
        int y = y0 - 1 + yr; y = y < 0 ? 0 : (y > 255 ? 255 : y);
        *(float4*)&zs[xi * ZSTR + yr * 64 + o] =
            *(const float4*)&zg[x * 16384 + y * 64 + o];
    }
    __syncthreads();

    // ---- compute: thread = (cell, k-quad) ----
    const int c  = tid >> 4;
    const int kq = tid & 15;
    const int cx = c & 3, cy = c >> 2;
    const int xg = x0 + cx, yg = y0 + cy;
    const int k0 = kq << 2;

    // b-field global loads: issue early (clamped addresses so edge threads
    // stay in bounds; their results are masked by the xg<255/yg<255 guard).
    const int xgc = xg > 254 ? 254 : xg;
    const int ygc = yg > 254 ? 254 : yg;
    const int t4  = (kq == 15) ? 0 : 4;
    const float* b0 = tg + (((size_t)bb * 3) << 22)
                         + (size_t)xgc * 16384 + (size_t)ygc * 64 + k0;
    const float* b1 = b0 + 4194304;
    const float* b2 = b0 + 8388608;

    float bx00v[5]; LDG5(bx00v, b0);
    float bx10v[5]; LDG5(bx10v, b0 + 16384);
    float bx01v[5]; LDG5(bx01v, b0 + 64);
    float bx11v[5]; LDG5(bx11v, b0 + 16448);
    float by00v[5]; LDG5(by00v, b1);
    float by10v[5]; LDG5(by10v, b1 + 16384);
    float by01v[5]; LDG5(by01v, b1 + 64);
    float by11v[5]; LDG5(by11v, b1 + 16448);
    float bz00v[5]; LDG5(bz00v, b2);
    float bz10v[5]; LDG5(bz10v, b2 + 16384);
    float bz01v[5]; LDG5(bz01v, b2 + 64);
    float bz11v[5]; LDG5(bz11v, b2 + 16448);

    const float* zC = &zs[(cx + 1) * ZSTR + (cy + 1) * 64 + k0];

    float zcv[7];
    {
        float4 m = *(const float4*)(zC - 4);
        float4 a = *(const float4*)(zC);
        float4 b = *(const float4*)(zC + 4);
        zcv[0] = m.w; zcv[1] = a.x; zcv[2] = a.y; zcv[3] = a.z; zcv[4] = a.w;
        zcv[5] = b.x; zcv[6] = b.y;
    }
    float zEv[5];  LD5(zEv,  zC + ZSTR);
    float zWv[5];  LD5(zWv,  zC - ZSTR);
    float zNv[5];  LD5(zNv,  zC + 64);
    float zSv[5];  LD5(zSv,  zC - 64);
    float zNEv[5]; LD5(zNEv, zC + ZSTR + 64);

    float dz0[4], dzE[4], dzN[4], dzNE[4];
    #pragma unroll
    for (int e = 0; e < 4; ++e) {
        dz0[e]  = zcv[e + 2] - zcv[e + 1];
        dzE[e]  = zEv[e + 1] - zEv[e];
        dzN[e]  = zNv[e + 1] - zNv[e];
        dzNE[e] = zNEv[e + 1] - zNEv[e];
    }

    // std partials (per-k): k<63 valid
    float s1a[4], s2a[4];
    #pragma unroll
    for (int e = 0; e < 4; ++e) {
        bool kok = (k0 + e) < 63;
        s1a[e] = kok ? dz0[e] : 0.0f;
        s2a[e] = kok ? dz0[e] * dz0[e] : 0.0f;
    }

    // smooth
    float sm = 0.0f;
    if (xg >= 1 && xg <= 254 && yg >= 1 && yg <= 254) {
        #pragma unroll
        for (int e = 0; e < 4; ++e) {
            int k = k0 + e;
            if (k >= 1 && k <= 61) {
                float dzm = zcv[e + 1] - zcv[e];
                float dzp = zcv[e + 3] - zcv[e + 2];
                float dzw = zWv[e + 1] - zWv[e];
                float dzs = zSv[e + 1] - zSv[e];
                float lap = 6.0f * dz0[e] * dz0[e]
                          - dzw * dzw - dzE[e] * dzE[e]
                          - dzs * dzs - dzN[e] * dzN[e]
                          - dzm * dzm - dzp * dzp;
                sm += lap * lap;
            }
        }
    }

    // div
    float dv = 0.0f;
    if (xg < 255 && yg < 255) {
        const float c6 = 1.0f / 6.0f;
        #pragma unroll
        for (int e = 0; e < 4; ++e) {
            if ((k0 + e) < 63) {
                float adz00 = fabsf(dz0[e]),  adz10 = fabsf(dzE[e]);
                float adz01 = fabsf(dzN[e]),  adz11 = fabsf(dzNE[e]);

                float num =
                    0.125f * ( (bx10v[e] + bx10v[e+1] + bx11v[e] + bx11v[e+1]) * (adz10 + adz11)
                             - (bx00v[e] + bx00v[e+1] + bx01v[e] + bx01v[e+1]) * (adz00 + adz01)
                             + (by01v[e] + by01v[e+1] + by11v[e] + by11v[e+1]) * (adz01 + adz11)
                             - (by00v[e] + by00v[e+1] + by10v[e] + by10v[e+1]) * (adz00 + adz10) )
                  + 0.25f * ( (bz00v[e+1] + bz10v[e+1] + bz01v[e+1] + bz11v[e+1])
                            - (bz00v[e]   + bz10v[e]   + bz01v[e]   + bz11v[e]) );

                num += c6 * ( (bx00v[e+1] + bx10v[e+1] + bx11v[e+1]) * (zcv[e+2] - zEv[e+1])
                            + (bx01v[e+1] + bx11v[e+1] + bx10v[e+1]) * (zNv[e+1] - zNEv[e+1])
                            + (by10v[e+1] + by11v[e+1] + by01v[e+1]) * (zEv[e+1] - zNEv[e+1])
                            + (by00v[e+1] + by01v[e+1] + by11v[e+1]) * (zcv[e+2] - zNv[e+1])
                            - (bx00v[e] + bx10v[e] + bx11v[e]) * (zcv[e+1] - zEv[e])
                            - (bx01v[e] + bx11v[e] + bx10v[e]) * (zNv[e] - zNEv[e])
                            - (by10v[e] + by11v[e] + by01v[e]) * (zEv[e] - zNEv[e])
                            - (by00v[e] + by01v[e] + by11v[e]) * (zcv[e+1] - zNv[e]) );

                float sbx = bx00v[e] + bx00v[e+1] + bx10v[e] + bx10v[e+1]
                          + bx01v[e] + bx01v[e+1] + bx11v[e] + bx11v[e+1];
                float sby = by00v[e] + by00v[e+1] + by10v[e] + by10v[e+1]
                          + by01v[e] + by01v[e+1] + by11v[e] + by11v[e+1];
                float sbz = bz00v[e] + bz00v[e+1] + bz10v[e] + bz10v[e+1]
                          + bz01v[e] + bz01v[e+1] + bz11v[e] + bz11v[e+1];
                float den = 0.015625f * (sbx * sbx + sby * sby + sbz * sbz) + 1e-10f;
                dv += num * num / den;
            }
        }
    }

    // ---- block reduction ----
    #pragma unroll
    for (int off = 32; off > 0; off >>= 1) {
        sm += __shfl_down(sm, off, 64);
        dv += __shfl_down(dv, off, 64);
    }

    __syncthreads();   // all LDS reads done; safe to reuse zs
    float* r1 = zs;            // 1024 floats
    float* r2 = zs + 1024;     // 1024 floats
    { float4 v; v.x = s1a[0]; v.y = s1a[1]; v.z = s1a[2]; v.w = s1a[3];
      *(float4*)&r1[tid << 2] = v; }
    { float4 v; v.x = s2a[0]; v.y = s2a[1]; v.z = s2a[2]; v.w = s2a[3];
      *(float4*)&r2[tid << 2] = v; }
    if (lane == 0) { rsc[w][0] = sm; rsc[w][1] = dv; }
    __syncthreads();

    if (tid < 64) {
        float a = 0.0f, b2r = 0.0f;
        #pragma unroll
        for (int cc = 0; cc < 16; ++cc) {
            a   += r1[cc * 64 + tid];
            b2r += r2[cc * 64 + tid];
        }
        float* sl = ws + (blockIdx.x & 31) * 258;
        if (tid < 63) {
            atomicAdd(&sl[2 + bb * 64 + tid],   a);
            atomicAdd(&sl[130 + bb * 64 + tid], b2r);
        }
        if (tid == 0) atomicAdd(&sl[0], rsc[0][0] + rsc[1][0] + rsc[2][0] + rsc[3][0]);
        if (tid == 1) atomicAdd(&sl[1], rsc[0][1] + rsc[1][1] + rsc[2][1] + rsc[3][1]);
    }
}

__global__ __launch_bounds__(128) void finalize_kernel(const float* __restrict__ ws,
                                                       float* __restrict__ out)
{
    __shared__ double red[128];
    const int t = threadIdx.x;
    double stdv = 0.0;
    {
        int k = t & 63, bb = t >> 6;
        if (k < 63) {
            double s1 = 0.0, s2 = 0.0;
            for (int p = 0; p < 32; ++p) {
                s1 += (double)ws[p * 258 + 2 + bb * 64 + k];
                s2 += (double)ws[p * 258 + 130 + bb * 64 + k];
            }
            const double N = 65536.0;
            double var = (s2 - s1 * s1 / N) / (N - 1.0);
            stdv = sqrt(var > 0.0 ? var : 0.0);
        }
    }
    red[t] = stdv;
    __syncthreads();
    for (int off = 64; off > 0; off >>= 1) {
        if (t < off) red[t] += red[t + off];
        __syncthreads();
    }
    if (t == 0) {
        double smt = 0.0, dvt = 0.0;
        for (int p = 0; p < 32; ++p) {
            smt += (double)ws[p * 258 + 0];
            dvt += (double)ws[p * 258 + 1];
        }
        double loss_std    = red[0] / 126.0;
        double loss_smooth = smt / (2.0 * 254.0 * 254.0 * 61.0);
        double loss_div    = dvt / (2.0 * 255.0 * 255.0 * 63.0);
        out[0] = (float)(loss_div * 1e9);
        out[1] = (float)(loss_smooth * 10.0 + loss_std * 100.0);
    }
}

extern "C" void kernel_launch(void* const* d_in, const int* in_sizes, int n_in,
                              void* d_out, int out_size, void* d_ws, size_t ws_size,
                              hipStream_t stream) {
    const float* z  = (const float*)d_in[0];   // outputs (2,1,256,256,64)
    const float* tg = (const float*)d_in[1];   // targets (2,3,256,256,64)
    float* out = (float*)d_out;
    float* ws  = (float*)d_ws;

    zero_ws_kernel<<<1, 512, 0, stream>>>(ws);
    // 64x64 tiles x 2 batches = 8192 blocks
    fused_loss_kernel<<<8192, 256, 0, stream>>>(z, tg, ws);
    finalize_kernel<<<1, 128, 0, stream>>>(ws, out);
}

// Round 2
// 294.728 us; speedup vs baseline: 1.4709x; 1.4709x over previous
//
#include <hip/hip_runtime.h>
#include <math.h>

// z:  (2,1,256,256,64)  idx = b*4194304 + x*16384 + y*64 + k
// tg: (2,3,256,256,64)  idx = b*12582912 + c*4194304 + x*16384 + y*64 + k
//
// Tiled stencil: block = 4x4 cells (x0..x0+3, y0..y0+3), full k (64).
// LDS: z strips only (x0-1..x0+4) x (y0-1..y0+4). 9.3 KB.
// b fields read directly from global as float4; the k0+4 element comes from
// the next kq-thread via __shfl_down (no 5-wide loads, no runtime index,
// no spill). Same for the z strip extensions (LDS reads halved: 13 -> 6).
// All shfls execute unconditionally (outside divergent guards); lane-edge
// garbage (kq==15 / kq==0) is masked by the k-range guards.
//
// ws layout (floats), 32 slices x 258:
//   sl[p*258 + 0]=smooth, +1=div, +2+b*64+k = s1, +130+b*64+k = s2

#define ZSTR 388            // 6*64 + 4 pad

__global__ __launch_bounds__(512) void zero_ws_kernel(float* ws) {
    for (int i = threadIdx.x; i < 32 * 258; i += 512) ws[i] = 0.0f;
}

__global__ __launch_bounds__(256, 4) void fused_loss_kernel(
    const float* __restrict__ zin, const float* __restrict__ tg,
    float* __restrict__ ws)
{
    __shared__ float zs[6 * ZSTR];       // 2328 floats = 9312 B
    __shared__ float rsc[4][2];

    const int tid  = threadIdx.x;
    const int lane = tid & 63;
    const int w    = tid >> 6;

    const int bb = blockIdx.x >> 12;
    const int rest = blockIdx.x & 4095;
    const int x0 = ((rest >> 6) & 63) << 2;
    const int y0 = (rest & 63) << 2;

    const float* zg = zin + ((size_t)bb << 22);

    // ---- cooperative staging: 576 z float4s ----
    for (int i = tid; i < 576; i += 256) {
        int row = i >> 4;
        int o   = (i & 15) << 2;
        int xi  = row / 6;
        int yr  = row - xi * 6;
        int x = x0 - 1 + xi; x = x < 0 ? 0 : (x > 255 ? 255 : x);
        int y = y0 - 1 + yr; y = y < 0 ? 0 : (y > 255 ? 255 : y);
        *(float4*)&zs[xi * ZSTR + yr * 64 + o] =
            *(const float4*)&zg[x * 16384 + y * 64 + o];
    }

    // ---- compute mapping: thread = (cell, k-quad) ----
    const int c  = tid >> 4;
    const int kq = tid & 15;
    const int cx = c & 3, cy = c >> 2;
    const int xg = x0 + cx, yg = y0 + cy;
    const int k0 = kq << 2;

    // b-field global loads: issue before the barrier to overlap staging.
    // Clamped addresses keep edge threads in bounds; results masked later.
    const int xgc = xg > 254 ? 254 : xg;
    const int ygc = yg > 254 ? 254 : yg;
    const float* bp0 = tg + (((size_t)bb * 3) << 22)
                          + (size_t)xgc * 16384 + (size_t)ygc * 64 + k0;
    const float* bp1 = bp0 + 4194304;
    const float* bp2 = bp0 + 8388608;

    float4 bx00 = *(const float4*)(bp0);
    float4 bx10 = *(const float4*)(bp0 + 16384);
    float4 bx01 = *(const float4*)(bp0 + 64);
    float4 bx11 = *(const float4*)(bp0 + 16448);
    float4 by00 = *(const float4*)(bp1);
    float4 by10 = *(const float4*)(bp1 + 16384);
    float4 by01 = *(const float4*)(bp1 + 64);
    float4 by11 = *(const float4*)(bp1 + 16448);
    float4 bz00 = *(const float4*)(bp2);
    float4 bz10 = *(const float4*)(bp2 + 16384);
    float4 bz01 = *(const float4*)(bp2 + 64);
    float4 bz11 = *(const float4*)(bp2 + 16448);

    __syncthreads();

    // ---- z fragments: one b128 each + shfl extension ----
    const float* zC = &zs[(cx + 1) * ZSTR + (cy + 1) * 64 + k0];

    float4 za   = *(const float4*)(zC);
    float4 zE4  = *(const float4*)(zC + ZSTR);
    float4 zW4  = *(const float4*)(zC - ZSTR);
    float4 zN4  = *(const float4*)(zC + 64);
    float4 zS4  = *(const float4*)(zC - 64);
    float4 zNE4 = *(const float4*)(zC + ZSTR + 64);

    // cross-lane extensions (unconditional — all lanes participate)
    float zcv[7];
    zcv[0] = __shfl_up(za.w, 1, 64);          // z[k0-1]; garbage kq==0 (k=0 masked)
    zcv[1] = za.x; zcv[2] = za.y; zcv[3] = za.z; zcv[4] = za.w;
    zcv[5] = __shfl_down(za.x, 1, 64);        // z[k0+4]; garbage kq==15 (masked)
    zcv[6] = __shfl_down(za.y, 1, 64);        // z[k0+5]; garbage kq==15 (masked)
    float zEv[5]  = {zE4.x,  zE4.y,  zE4.z,  zE4.w,  __shfl_down(zE4.x,  1, 64)};
    float zWv[5]  = {zW4.x,  zW4.y,  zW4.z,  zW4.w,  __shfl_down(zW4.x,  1, 64)};
    float zNv[5]  = {zN4.x,  zN4.y,  zN4.z,  zN4.w,  __shfl_down(zN4.x,  1, 64)};
    float zSv[5]  = {zS4.x,  zS4.y,  zS4.z,  zS4.w,  __shfl_down(zS4.x,  1, 64)};
    float zNEv[5] = {zNE4.x, zNE4.y, zNE4.z, zNE4.w, __shfl_down(zNE4.x, 1, 64)};

    // b 5th elements (also unconditional, before any divergent guard)
    float bx00t = __shfl_down(bx00.x, 1, 64);
    float bx10t = __shfl_down(bx10.x, 1, 64);
    float bx01t = __shfl_down(bx01.x, 1, 64);
    float bx11t = __shfl_down(bx11.x, 1, 64);
    float by00t = __shfl_down(by00.x, 1, 64);
    float by10t = __shfl_down(by10.x, 1, 64);
    float by01t = __shfl_down(by01.x, 1, 64);
    float by11t = __shfl_down(by11.x, 1, 64);
    float bz00t = __shfl_down(bz00.x, 1, 64);
    float bz10t = __shfl_down(bz10.x, 1, 64);
    float bz01t = __shfl_down(bz01.x, 1, 64);
    float bz11t = __shfl_down(bz11.x, 1, 64);

    float dz0[4], dzE[4], dzN[4], dzNE[4];
    #pragma unroll
    for (int e = 0; e < 4; ++e) {
        dz0[e]  = zcv[e + 2] - zcv[e + 1];
        dzE[e]  = zEv[e + 1] - zEv[e];
        dzN[e]  = zNv[e + 1] - zNv[e];
        dzNE[e] = zNEv[e + 1] - zNEv[e];
    }

    // smooth
    float sm = 0.0f;
    if (xg >= 1 && xg <= 254 && yg >= 1 && yg <= 254) {
        #pragma unroll
        for (int e = 0; e < 4; ++e) {
            int k = k0 + e;
            if (k >= 1 && k <= 61) {
                float dzm = zcv[e + 1] - zcv[e];
                float dzp = zcv[e + 3] - zcv[e + 2];
                float dzw = zWv[e + 1] - zWv[e];
                float dzs = zSv[e + 1] - zSv[e];
                float lap = 6.0f * dz0[e] * dz0[e]
                          - dzw * dzw - dzE[e] * dzE[e]
                          - dzs * dzs - dzN[e] * dzN[e]
                          - dzm * dzm - dzp * dzp;
                sm += lap * lap;
            }
        }
    }

    // div
    float dv = 0.0f;
    if (xg < 255 && yg < 255) {
        float bx00v[5] = {bx00.x, bx00.y, bx00.z, bx00.w, bx00t};
        float bx10v[5] = {bx10.x, bx10.y, bx10.z, bx10.w, bx10t};
        float bx01v[5] = {bx01.x, bx01.y, bx01.z, bx01.w, bx01t};
        float bx11v[5] = {bx11.x, bx11.y, bx11.z, bx11.w, bx11t};
        float by00v[5] = {by00.x, by00.y, by00.z, by00.w, by00t};
        float by10v[5] = {by10.x, by10.y, by10.z, by10.w, by10t};
        float by01v[5] = {by01.x, by01.y, by01.z, by01.w, by01t};
        float by11v[5] = {by11.x, by11.y, by11.z, by11.w, by11t};
        float bz00v[5] = {bz00.x, bz00.y, bz00.z, bz00.w, bz00t};
        float bz10v[5] = {bz10.x, bz10.y, bz10.z, bz10.w, bz10t};
        float bz01v[5] = {bz01.x, bz01.y, bz01.z, bz01.w, bz01t};
        float bz11v[5] = {bz11.x, bz11.y, bz11.z, bz11.w, bz11t};

        const float c6 = 1.0f / 6.0f;
        #pragma unroll
        for (int e = 0; e < 4; ++e) {
            if ((k0 + e) < 63) {
                float adz00 = fabsf(dz0[e]),  adz10 = fabsf(dzE[e]);
                float adz01 = fabsf(dzN[e]),  adz11 = fabsf(dzNE[e]);

                float num =
                    0.125f * ( (bx10v[e] + bx10v[e+1] + bx11v[e] + bx11v[e+1]) * (adz10 + adz11)
                             - (bx00v[e] + bx00v[e+1] + bx01v[e] + bx01v[e+1]) * (adz00 + adz01)
                             + (by01v[e] + by01v[e+1] + by11v[e] + by11v[e+1]) * (adz01 + adz11)
                             - (by00v[e] + by00v[e+1] + by10v[e] + by10v[e+1]) * (adz00 + adz10) )
                  + 0.25f * ( (bz00v[e+1] + bz10v[e+1] + bz01v[e+1] + bz11v[e+1])
                            - (bz00v[e]   + bz10v[e]   + bz01v[e]   + bz11v[e]) );

                num += c6 * ( (bx00v[e+1] + bx10v[e+1] + bx11v[e+1]) * (zcv[e+2] - zEv[e+1])
                            + (bx01v[e+1] + bx11v[e+1] + bx10v[e+1]) * (zNv[e+1] - zNEv[e+1])
                            + (by10v[e+1] + by11v[e+1] + by01v[e+1]) * (zEv[e+1] - zNEv[e+1])
                            + (by00v[e+1] + by01v[e+1] + by11v[e+1]) * (zcv[e+2] - zNv[e+1])
                            - (bx00v[e] + bx10v[e] + bx11v[e]) * (zcv[e+1] - zEv[e])
                            - (bx01v[e] + bx11v[e] + bx10v[e]) * (zNv[e] - zNEv[e])
                            - (by10v[e] + by11v[e] + by01v[e]) * (zEv[e] - zNEv[e])
                            - (by00v[e] + by01v[e] + by11v[e]) * (zcv[e+1] - zNv[e]) );

                float sbx = bx00v[e] + bx00v[e+1] + bx10v[e] + bx10v[e+1]
                          + bx01v[e] + bx01v[e+1] + bx11v[e] + bx11v[e+1];
                float sby = by00v[e] + by00v[e+1] + by10v[e] + by10v[e+1]
                          + by01v[e] + by01v[e+1] + by11v[e] + by11v[e+1];
                float sbz = bz00v[e] + bz00v[e+1] + bz10v[e] + bz10v[e+1]
                          + bz01v[e] + bz01v[e+1] + bz11v[e] + bz11v[e+1];
                float den = 0.015625f * (sbx * sbx + sby * sby + sbz * sbz) + 1e-10f;
                dv += num * num / den;
            }
        }
    }

    // ---- block reduction ----
    #pragma unroll
    for (int off = 32; off > 0; off >>= 1) {
        sm += __shfl_down(sm, off, 64);
        dv += __shfl_down(dv, off, 64);
    }

    __syncthreads();   // all LDS reads done; safe to reuse zs
    float* r1 = zs;            // 1024 floats
    float* r2 = zs + 1024;     // 1024 floats
    {
        // std partials computed at write time (k<63 valid)
        float4 v1, v2;
        float d;
        d = (k0 + 0) < 63 ? dz0[0] : 0.0f; v1.x = d; v2.x = d * d;
        d = (k0 + 1) < 63 ? dz0[1] : 0.0f; v1.y = d; v2.y = d * d;
        d = (k0 + 2) < 63 ? dz0[2] : 0.0f; v1.z = d; v2.z = d * d;
        d = (k0 + 3) < 63 ? dz0[3] : 0.0f; v1.w = d; v2.w = d * d;
        *(float4*)&r1[tid << 2] = v1;
        *(float4*)&r2[tid << 2] = v2;
    }
    if (lane == 0) { rsc[w][0] = sm; rsc[w][1] = dv; }
    __syncthreads();

    if (tid < 64) {
        float a = 0.0f, b2r = 0.0f;
        #pragma unroll
        for (int cc = 0; cc < 16; ++cc) {
            a   += r1[cc * 64 + tid];
            b2r += r2[cc * 64 + tid];
        }
        float* sl = ws + (blockIdx.x & 31) * 258;
        if (tid < 63) {
            atomicAdd(&sl[2 + bb * 64 + tid],   a);
            atomicAdd(&sl[130 + bb * 64 + tid], b2r);
        }
        if (tid == 0) atomicAdd(&sl[0], rsc[0][0] + rsc[1][0] + rsc[2][0] + rsc[3][0]);
        if (tid == 1) atomicAdd(&sl[1], rsc[0][1] + rsc[1][1] + rsc[2][1] + rsc[3][1]);
    }
}

__global__ __launch_bounds__(128) void finalize_kernel(const float* __restrict__ ws,
                                                       float* __restrict__ out)
{
    __shared__ double red[128];
    const int t = threadIdx.x;
    double stdv = 0.0;
    {
        int k = t & 63, bb = t >> 6;
        if (k < 63) {
            double s1 = 0.0, s2 = 0.0;
            for (int p = 0; p < 32; ++p) {
                s1 += (double)ws[p * 258 + 2 + bb * 64 + k];
                s2 += (double)ws[p * 258 + 130 + bb * 64 + k];
            }
            const double N = 65536.0;
            double var = (s2 - s1 * s1 / N) / (N - 1.0);
            stdv = sqrt(var > 0.0 ? var : 0.0);
        }
    }
    red[t] = stdv;
    __syncthreads();
    for (int off = 64; off > 0; off >>= 1) {
        if (t < off) red[t] += red[t + off];
        __syncthreads();
    }
    if (t == 0) {
        double smt = 0.0, dvt = 0.0;
        for (int p = 0; p < 32; ++p) {
            smt += (double)ws[p * 258 + 0];
            dvt += (double)ws[p * 258 + 1];
        }
        double loss_std    = red[0] / 126.0;
        double loss_smooth = smt / (2.0 * 254.0 * 254.0 * 61.0);
        double loss_div    = dvt / (2.0 * 255.0 * 255.0 * 63.0);
        out[0] = (float)(loss_div * 1e9);
        out[1] = (float)(loss_smooth * 10.0 + loss_std * 100.0);
    }
}

extern "C" void kernel_launch(void* const* d_in, const int* in_sizes, int n_in,
                              void* d_out, int out_size, void* d_ws, size_t ws_size,
                              hipStream_t stream) {
    const float* z  = (const float*)d_in[0];   // outputs (2,1,256,256,64)
    const float* tg = (const float*)d_in[1];   // targets (2,3,256,256,64)
    float* out = (float*)d_out;
    float* ws  = (float*)d_ws;

    zero_ws_kernel<<<1, 512, 0, stream>>>(ws);
    // 64x64 tiles x 2 batches = 8192 blocks
    fused_loss_kernel<<<8192, 256, 0, stream>>>(z, tg, ws);
    finalize_kernel<<<1, 128, 0, stream>>>(ws, out);
}

// Round 3
// 255.366 us; speedup vs baseline: 1.6977x; 1.1541x over previous
//
#include <hip/hip_runtime.h>
#include <math.h>

// z:  (2,1,256,256,64)  idx = b*4194304 + x*16384 + y*64 + k
// tg: (2,3,256,256,64)  idx = b*12582912 + c*4194304 + x*16384 + y*64 + k
//
// Tiled stencil: block = 4x4 cells, full k (64). LDS: z strips only (9.3 KB).
// b fields read directly from global as float4; element k0+4 comes from the
// next kq-thread via __shfl_down.
//
// CRITICAL: no local float arrays anywhere in the hot path. Round 1/2 showed
// the compiler lowers float v[5] = {...} to SCRATCH (128-240 B/thread, 266+ MB
// of HBM scratch writes). All 5-element "arrays" are a float4 + named tail
// scalar, accessed via the EL5() constant-folding selector inside #pragma
// unroll loops (index is a literal after unroll -> folds to one component,
// no alloca, no scratch).
//
// ws layout (floats), 32 slices x 258:
//   sl[p*258 + 0]=smooth, +1=div, +2+b*64+k = s1, +130+b*64+k = s2

#define ZSTR 388            // 6*64 + 4 pad

__global__ __launch_bounds__(512) void zero_ws_kernel(float* ws) {
    for (int i = threadIdx.x; i < 32 * 258; i += 512) ws[i] = 0.0f;
}

// constant-folding 5-element selector: v.x..v.w for i=0..3, tail t for i=4
#define EL5(v, t, i) \
    ((i) == 0 ? (v).x : (i) == 1 ? (v).y : (i) == 2 ? (v).z : (i) == 3 ? (v).w : (t))

__global__ __launch_bounds__(256, 4) void fused_loss_kernel(
    const float* __restrict__ zin, const float* __restrict__ tg,
    float* __restrict__ ws)
{
    __shared__ float zs[6 * ZSTR];       // 2328 floats = 9312 B
    __shared__ float rsc[4][2];

    const int tid  = threadIdx.x;
    const int lane = tid & 63;
    const int w    = tid >> 6;

    const int bb = blockIdx.x >> 12;
    const int rest = blockIdx.x & 4095;
    const int x0 = ((rest >> 6) & 63) << 2;
    const int y0 = (rest & 63) << 2;

    const float* zg = zin + ((size_t)bb << 22);

    // ---- cooperative staging: 576 z float4s ----
    for (int i = tid; i < 576; i += 256) {
        int row = i >> 4;
        int o   = (i & 15) << 2;
        int xi  = row / 6;
        int yr  = row - xi * 6;
        int x = x0 - 1 + xi; x = x < 0 ? 0 : (x > 255 ? 255 : x);
        int y = y0 - 1 + yr; y = y < 0 ? 0 : (y > 255 ? 255 : y);
        *(float4*)&zs[xi * ZSTR + yr * 64 + o] =
            *(const float4*)&zg[x * 16384 + y * 64 + o];
    }

    // ---- compute mapping: thread = (cell, k-quad) ----
    const int c  = tid >> 4;
    const int kq = tid & 15;
    const int cx = c & 3, cy = c >> 2;
    const int xg = x0 + cx, yg = y0 + cy;
    const int k0 = kq << 2;

    // b-field global loads: issue before the barrier to overlap staging.
    const int xgc = xg > 254 ? 254 : xg;
    const int ygc = yg > 254 ? 254 : yg;
    const float* bp0 = tg + (((size_t)bb * 3) << 22)
                          + (size_t)xgc * 16384 + (size_t)ygc * 64 + k0;
    const float* bp1 = bp0 + 4194304;
    const float* bp2 = bp0 + 8388608;

    float4 bx00 = *(const float4*)(bp0);
    float4 bx10 = *(const float4*)(bp0 + 16384);
    float4 bx01 = *(const float4*)(bp0 + 64);
    float4 bx11 = *(const float4*)(bp0 + 16448);
    float4 by00 = *(const float4*)(bp1);
    float4 by10 = *(const float4*)(bp1 + 16384);
    float4 by01 = *(const float4*)(bp1 + 64);
    float4 by11 = *(const float4*)(bp1 + 16448);
    float4 bz00 = *(const float4*)(bp2);
    float4 bz10 = *(const float4*)(bp2 + 16384);
    float4 bz01 = *(const float4*)(bp2 + 64);
    float4 bz11 = *(const float4*)(bp2 + 16448);

    __syncthreads();

    // ---- z fragments: one ds_read_b128 each + shfl tails ----
    const float* zC = &zs[(cx + 1) * ZSTR + (cy + 1) * 64 + k0];

    float4 za   = *(const float4*)(zC);
    float4 zE4  = *(const float4*)(zC + ZSTR);
    float4 zW4  = *(const float4*)(zC - ZSTR);
    float4 zN4  = *(const float4*)(zC + 64);
    float4 zS4  = *(const float4*)(zC - 64);
    float4 zNE4 = *(const float4*)(zC + ZSTR + 64);

    // cross-lane tails (unconditional; lane-edge garbage masked by k guards)
    float zcm1 = __shfl_up(za.w, 1, 64);       // z[k0-1]; garbage kq==0 (k=0 masked)
    float zp4  = __shfl_down(za.x, 1, 64);     // z[k0+4]; garbage kq==15 (masked)
    float zp5  = __shfl_down(za.y, 1, 64);     // z[k0+5]; garbage kq==15 (masked)
    float zEt  = __shfl_down(zE4.x,  1, 64);
    float zWt  = __shfl_down(zW4.x,  1, 64);
    float zNt  = __shfl_down(zN4.x,  1, 64);
    float zSt  = __shfl_down(zS4.x,  1, 64);
    float zNEt = __shfl_down(zNE4.x, 1, 64);

    float bx00t = __shfl_down(bx00.x, 1, 64);
    float bx10t = __shfl_down(bx10.x, 1, 64);
    float bx01t = __shfl_down(bx01.x, 1, 64);
    float bx11t = __shfl_down(bx11.x, 1, 64);
    float by00t = __shfl_down(by00.x, 1, 64);
    float by10t = __shfl_down(by10.x, 1, 64);
    float by01t = __shfl_down(by01.x, 1, 64);
    float by11t = __shfl_down(by11.x, 1, 64);
    float bz00t = __shfl_down(bz00.x, 1, 64);
    float bz10t = __shfl_down(bz10.x, 1, 64);
    float bz01t = __shfl_down(bz01.x, 1, 64);
    float bz11t = __shfl_down(bz11.x, 1, 64);

    // selectors (indices become literals after #pragma unroll)
    #define ZC7(i) ((i) == 0 ? zcm1 : (i) == 1 ? za.x : (i) == 2 ? za.y : \
                    (i) == 3 ? za.z : (i) == 4 ? za.w : (i) == 5 ? zp4 : zp5)
    #define ZE(i)   EL5(zE4,  zEt,  i)
    #define ZW(i)   EL5(zW4,  zWt,  i)
    #define ZN(i)   EL5(zN4,  zNt,  i)
    #define ZS(i)   EL5(zS4,  zSt,  i)
    #define ZNE(i)  EL5(zNE4, zNEt, i)
    #define BX00(i) EL5(bx00, bx00t, i)
    #define BX10(i) EL5(bx10, bx10t, i)
    #define BX01(i) EL5(bx01, bx01t, i)
    #define BX11(i) EL5(bx11, bx11t, i)
    #define BY00(i) EL5(by00, by00t, i)
    #define BY10(i) EL5(by10, by10t, i)
    #define BY01(i) EL5(by01, by01t, i)
    #define BY11(i) EL5(by11, by11t, i)
    #define BZ00(i) EL5(bz00, bz00t, i)
    #define BZ10(i) EL5(bz10, bz10t, i)
    #define BZ01(i) EL5(bz01, bz01t, i)
    #define BZ11(i) EL5(bz11, bz11t, i)

    // smooth
    float sm = 0.0f;
    if (xg >= 1 && xg <= 254 && yg >= 1 && yg <= 254) {
        #pragma unroll
        for (int e = 0; e < 4; ++e) {
            int k = k0 + e;
            if (k >= 1 && k <= 61) {
                float dz0e = ZC7(e + 2) - ZC7(e + 1);
                float dzm  = ZC7(e + 1) - ZC7(e);
                float dzp  = ZC7(e + 3) - ZC7(e + 2);
                float dzw  = ZW(e + 1) - ZW(e);
                float dzs  = ZS(e + 1) - ZS(e);
                float dze  = ZE(e + 1) - ZE(e);
                float dzn  = ZN(e + 1) - ZN(e);
                float lap = 6.0f * dz0e * dz0e
                          - dzw * dzw - dze * dze
                          - dzs * dzs - dzn * dzn
                          - dzm * dzm - dzp * dzp;
                sm += lap * lap;
            }
        }
    }

    // div
    float dv = 0.0f;
    if (xg < 255 && yg < 255) {
        const float c6 = 1.0f / 6.0f;
        #pragma unroll
        for (int e = 0; e < 4; ++e) {
            if ((k0 + e) < 63) {
                float dz0e  = ZC7(e + 2) - ZC7(e + 1);
                float dzEe  = ZE(e + 1) - ZE(e);
                float dzNe  = ZN(e + 1) - ZN(e);
                float dzNEe = ZNE(e + 1) - ZNE(e);
                float adz00 = fabsf(dz0e),  adz10 = fabsf(dzEe);
                float adz01 = fabsf(dzNe),  adz11 = fabsf(dzNEe);

                float num =
                    0.125f * ( (BX10(e) + BX10(e+1) + BX11(e) + BX11(e+1)) * (adz10 + adz11)
                             - (BX00(e) + BX00(e+1) + BX01(e) + BX01(e+1)) * (adz00 + adz01)
                             + (BY01(e) + BY01(e+1) + BY11(e) + BY11(e+1)) * (adz01 + adz11)
                             - (BY00(e) + BY00(e+1) + BY10(e) + BY10(e+1)) * (adz00 + adz10) )
                  + 0.25f * ( (BZ00(e+1) + BZ10(e+1) + BZ01(e+1) + BZ11(e+1))
                            - (BZ00(e)   + BZ10(e)   + BZ01(e)   + BZ11(e)) );

                num += c6 * ( (BX00(e+1) + BX10(e+1) + BX11(e+1)) * (ZC7(e+2) - ZE(e+1))
                            + (BX01(e+1) + BX11(e+1) + BX10(e+1)) * (ZN(e+1) - ZNE(e+1))
                            + (BY10(e+1) + BY11(e+1) + BY01(e+1)) * (ZE(e+1) - ZNE(e+1))
                            + (BY00(e+1) + BY01(e+1) + BY11(e+1)) * (ZC7(e+2) - ZN(e+1))
                            - (BX00(e) + BX10(e) + BX11(e)) * (ZC7(e+1) - ZE(e))
                            - (BX01(e) + BX11(e) + BX10(e)) * (ZN(e) - ZNE(e))
                            - (BY10(e) + BY11(e) + BY01(e)) * (ZE(e) - ZNE(e))
                            - (BY00(e) + BY01(e) + BY11(e)) * (ZC7(e+1) - ZN(e)) );

                float sbx = BX00(e) + BX00(e+1) + BX10(e) + BX10(e+1)
                          + BX01(e) + BX01(e+1) + BX11(e) + BX11(e+1);
                float sby = BY00(e) + BY00(e+1) + BY10(e) + BY10(e+1)
                          + BY01(e) + BY01(e+1) + BY11(e) + BY11(e+1);
                float sbz = BZ00(e) + BZ00(e+1) + BZ10(e) + BZ10(e+1)
                          + BZ01(e) + BZ01(e+1) + BZ11(e) + BZ11(e+1);
                float den = 0.015625f * (sbx * sbx + sby * sby + sbz * sbz) + 1e-10f;
                dv += num * num / den;
            }
        }
    }

    // ---- block reduction ----
    #pragma unroll
    for (int off = 32; off > 0; off >>= 1) {
        sm += __shfl_down(sm, off, 64);
        dv += __shfl_down(dv, off, 64);
    }

    __syncthreads();   // all LDS reads done; safe to reuse zs
    float* r1 = zs;            // 1024 floats
    float* r2 = zs + 1024;     // 1024 floats
    {
        // std partials computed at write time (k<63 valid)
        float4 v1, v2;
        float d;
        d = (k0 + 0) < 63 ? (ZC7(2) - ZC7(1)) : 0.0f; v1.x = d; v2.x = d * d;
        d = (k0 + 1) < 63 ? (ZC7(3) - ZC7(2)) : 0.0f; v1.y = d; v2.y = d * d;
        d = (k0 + 2) < 63 ? (ZC7(4) - ZC7(3)) : 0.0f; v1.z = d; v2.z = d * d;
        d = (k0 + 3) < 63 ? (ZC7(5) - ZC7(4)) : 0.0f; v1.w = d; v2.w = d * d;
        *(float4*)&r1[tid << 2] = v1;
        *(float4*)&r2[tid << 2] = v2;
    }
    if (lane == 0) { rsc[w][0] = sm; rsc[w][1] = dv; }
    __syncthreads();

    if (tid < 64) {
        float a = 0.0f, b2r = 0.0f;
        #pragma unroll
        for (int cc = 0; cc < 16; ++cc) {
            a   += r1[cc * 64 + tid];
            b2r += r2[cc * 64 + tid];
        }
        float* sl = ws + (blockIdx.x & 31) * 258;
        if (tid < 63) {
            atomicAdd(&sl[2 + bb * 64 + tid],   a);
            atomicAdd(&sl[130 + bb * 64 + tid], b2r);
        }
        if (tid == 0) atomicAdd(&sl[0], rsc[0][0] + rsc[1][0] + rsc[2][0] + rsc[3][0]);
        if (tid == 1) atomicAdd(&sl[1], rsc[0][1] + rsc[1][1] + rsc[2][1] + rsc[3][1]);
    }
}

__global__ __launch_bounds__(128) void finalize_kernel(const float* __restrict__ ws,
                                                       float* __restrict__ out)
{
    __shared__ double red[128];
    const int t = threadIdx.x;
    double stdv = 0.0;
    {
        int k = t & 63, bb = t >> 6;
        if (k < 63) {
            double s1 = 0.0, s2 = 0.0;
            for (int p = 0; p < 32; ++p) {
                s1 += (double)ws[p * 258 + 2 + bb * 64 + k];
                s2 += (double)ws[p * 258 + 130 + bb * 64 + k];
            }
            const double N = 65536.0;
            double var = (s2 - s1 * s1 / N) / (N - 1.0);
            stdv = sqrt(var > 0.0 ? var : 0.0);
        }
    }
    red[t] = stdv;
    __syncthreads();
    for (int off = 64; off > 0; off >>= 1) {
        if (t < off) red[t] += red[t + off];
        __syncthreads();
    }
    if (t == 0) {
        double smt = 0.0, dvt = 0.0;
        for (int p = 0; p < 32; ++p) {
            smt += (double)ws[p * 258 + 0];
            dvt += (double)ws[p * 258 + 1];
        }
        double loss_std    = red[0] / 126.0;
        double loss_smooth = smt / (2.0 * 254.0 * 254.0 * 61.0);
        double loss_div    = dvt / (2.0 * 255.0 * 255.0 * 63.0);
        out[0] = (float)(loss_div * 1e9);
        out[1] = (float)(loss_smooth * 10.0 + loss_std * 100.0);
    }
}

extern "C" void kernel_launch(void* const* d_in, const int* in_sizes, int n_in,
                              void* d_out, int out_size, void* d_ws, size_t ws_size,
                              hipStream_t stream) {
    const float* z  = (const float*)d_in[0];   // outputs (2,1,256,256,64)
    const float* tg = (const float*)d_in[1];   // targets (2,3,256,256,64)
    float* out = (float*)d_out;
    float* ws  = (float*)d_ws;

    zero_ws_kernel<<<1, 512, 0, stream>>>(ws);
    // 64x64 tiles x 2 batches = 8192 blocks
    fused_loss_kernel<<<8192, 256, 0, stream>>>(z, tg, ws);
    finalize_kernel<<<1, 128, 0, stream>>>(ws, out);
}

// Round 4
// 206.251 us; speedup vs baseline: 2.1019x; 1.2381x over previous
//
#include <hip/hip_runtime.h>
#include <math.h>

// z:  (2,1,256,256,64)  idx = b*4194304 + x*16384 + y*64 + k
// tg: (2,3,256,256,64)  idx = b*12582912 + c*4194304 + x*16384 + y*64 + k
//
// Tiled stencil: block = 4x4 cells (x0..x0+3, y0..y0+3), full k (64).
// LDS: z strips x0-1..x0+4 (6) x rows y0-1..y0+4 (6); b fields x0..x0+4 (5) x y0..y0+4 (5).
// Strips padded +4 floats (also makes the scalar tail reads below in-bounds).
//
// Lesson from rounds 1-3: operands must be sourced from LDS. Values held in
// registers across the barrier from GLOBAL loads get spilled to scratch
// (98-130 B/thread, 200-266 MB of HBM scratch traffic); the identical arrays
// filled from LDS reads do not spill (compiler sinks/reschedules the ds_reads
// near their uses). So z AND b both stage through LDS (round-0 structure).
// This round's change: 5-wide reads are 1x ds_read_b128 + 1x ds_read_b32
// (was 2x ds_read_b128) -> 34% less LDS issue, fewer conflict-exposed reads.
// The tail element at kq==15 reads padded/neighbor data; every use of it is
// masked by the k<63 / k<=61 guards (verified absmax==0 in rounds 2-3).
//
// ws layout (floats), 32 slices x 258:
//   sl[p*258 + 0]=smooth, +1=div, +2+b*64+k = s1, +130+b*64+k = s2

#define ZSTR 388            // 6*64 + 4 pad
#define BSTR 324            // 5*64 + 4 pad
#define BFLD 1620           // 5*BSTR

__global__ __launch_bounds__(512) void zero_ws_kernel(float* ws) {
    for (int i = threadIdx.x; i < 32 * 258; i += 512) ws[i] = 0.0f;
}

// 5-wide LDS read: one b128 + one scalar tail (pad keeps (p)[4] in-bounds)
#define LD5(arr, p) do { \
    float4 _a = *(const float4*)(p); \
    arr[0] = _a.x; arr[1] = _a.y; arr[2] = _a.z; arr[3] = _a.w; \
    arr[4] = (p)[4]; } while (0)

__global__ __launch_bounds__(256, 4) void fused_loss_kernel(
    const float* __restrict__ zin, const float* __restrict__ tg,
    float* __restrict__ ws)
{
    __shared__ float zs[6 * ZSTR];       // 2328 floats
    __shared__ float bs[3 * BFLD];       // 4860 floats
    __shared__ float rsc[4][2];

    const int tid  = threadIdx.x;
    const int lane = tid & 63;
    const int w    = tid >> 6;

    const int bb = blockIdx.x >> 12;
    const int rest = blockIdx.x & 4095;
    const int x0 = ((rest >> 6) & 63) << 2;
    const int y0 = (rest & 63) << 2;

    const float* zg = zin + ((size_t)bb << 22);

    // ---- cooperative staging: 576 z float4s + 1200 b float4s ----
    for (int i = tid; i < 1776; i += 256) {
        if (i < 576) {
            int row = i >> 4;
            int o   = (i & 15) << 2;
            int xi  = row / 6;
            int yr  = row - xi * 6;
            int x = x0 - 1 + xi; x = x < 0 ? 0 : (x > 255 ? 255 : x);
            int y = y0 - 1 + yr; y = y < 0 ? 0 : (y > 255 ? 255 : y);
            *(float4*)&zs[xi * ZSTR + yr * 64 + o] =
                *(const float4*)&zg[x * 16384 + y * 64 + o];
        } else {
            int j  = i - 576;
            int f  = j / 400;
            int jj = j - f * 400;
            int row = jj >> 4;
            int o   = (jj & 15) << 2;
            int xi  = row / 5;
            int yr  = row - xi * 5;
            int x = x0 + xi; x = x > 255 ? 255 : x;
            int y = y0 + yr; y = y > 255 ? 255 : y;
            const float* g = tg + ((size_t)(bb * 3 + f) << 22);
            *(float4*)&bs[f * BFLD + xi * BSTR + yr * 64 + o] =
                *(const float4*)&g[x * 16384 + y * 64 + o];
        }
    }
    __syncthreads();

    // ---- compute: thread = (cell, k-quad) ----
    const int c  = tid >> 4;
    const int kq = tid & 15;
    const int cx = c & 3, cy = c >> 2;
    const int xg = x0 + cx, yg = y0 + cy;
    const int k0 = kq << 2;

    const float* zC = &zs[(cx + 1) * ZSTR + (cy + 1) * 64 + k0];

    float zcv[7];
    {
        float4 a = *(const float4*)(zC);
        zcv[0] = zC[-1];                 // k0-1; kq==0 reads prev row (k=0 masked)
        zcv[1] = a.x; zcv[2] = a.y; zcv[3] = a.z; zcv[4] = a.w;
        zcv[5] = zC[4];                  // kq==15 -> pad/next row (masked)
        zcv[6] = zC[5];
    }
    float zEv[5];  LD5(zEv,  zC + ZSTR);
    float zWv[5];  LD5(zWv,  zC - ZSTR);
    float zNv[5];  LD5(zNv,  zC + 64);
    float zSv[5];  LD5(zSv,  zC - 64);
    float zNEv[5]; LD5(zNEv, zC + ZSTR + 64);

    float dz0[4], dzE[4], dzN[4], dzNE[4];
    #pragma unroll
    for (int e = 0; e < 4; ++e) {
        dz0[e]  = zcv[e + 2] - zcv[e + 1];
        dzE[e]  = zEv[e + 1] - zEv[e];
        dzN[e]  = zNv[e + 1] - zNv[e];
        dzNE[e] = zNEv[e + 1] - zNEv[e];
    }

    // std partials (per-k): k<63 valid
    float s1a[4], s2a[4];
    #pragma unroll
    for (int e = 0; e < 4; ++e) {
        bool kok = (k0 + e) < 63;
        s1a[e] = kok ? dz0[e] : 0.0f;
        s2a[e] = kok ? dz0[e] * dz0[e] : 0.0f;
    }

    // smooth
    float sm = 0.0f;
    if (xg >= 1 && xg <= 254 && yg >= 1 && yg <= 254) {
        #pragma unroll
        for (int e = 0; e < 4; ++e) {
            int k = k0 + e;
            if (k >= 1 && k <= 61) {
                float dzm = zcv[e + 1] - zcv[e];
                float dzp = zcv[e + 3] - zcv[e + 2];
                float dzw = zWv[e + 1] - zWv[e];
                float dzs = zSv[e + 1] - zSv[e];
                float lap = 6.0f * dz0[e] * dz0[e]
                          - dzw * dzw - dzE[e] * dzE[e]
                          - dzs * dzs - dzN[e] * dzN[e]
                          - dzm * dzm - dzp * dzp;
                sm += lap * lap;
            }
        }
    }

    // div
    float dv = 0.0f;
    if (xg < 255 && yg < 255) {
        const float* bxP = &bs[cx * BSTR + cy * 64 + k0];
        const float* byP = bxP + BFLD;
        const float* bzP = byP + BFLD;
        float bx00v[5]; LD5(bx00v, bxP);
        float bx10v[5]; LD5(bx10v, bxP + BSTR);
        float bx01v[5]; LD5(bx01v, bxP + 64);
        float bx11v[5]; LD5(bx11v, bxP + BSTR + 64);
        float by00v[5]; LD5(by00v, byP);
        float by10v[5]; LD5(by10v, byP + BSTR);
        float by01v[5]; LD5(by01v, byP + 64);
        float by11v[5]; LD5(by11v, byP + BSTR + 64);
        float bz00v[5]; LD5(bz00v, bzP);
        float bz10v[5]; LD5(bz10v, bzP + BSTR);
        float bz01v[5]; LD5(bz01v, bzP + 64);
        float bz11v[5]; LD5(bz11v, bzP + BSTR + 64);

        const float c6 = 1.0f / 6.0f;
        #pragma unroll
        for (int e = 0; e < 4; ++e) {
            if ((k0 + e) < 63) {
                float adz00 = fabsf(dz0[e]),  adz10 = fabsf(dzE[e]);
                float adz01 = fabsf(dzN[e]),  adz11 = fabsf(dzNE[e]);

                float num =
                    0.125f * ( (bx10v[e] + bx10v[e+1] + bx11v[e] + bx11v[e+1]) * (adz10 + adz11)
                             - (bx00v[e] + bx00v[e+1] + bx01v[e] + bx01v[e+1]) * (adz00 + adz01)
                             + (by01v[e] + by01v[e+1] + by11v[e] + by11v[e+1]) * (adz01 + adz11)
                             - (by00v[e] + by00v[e+1] + by10v[e] + by10v[e+1]) * (adz00 + adz10) )
                  + 0.25f * ( (bz00v[e+1] + bz10v[e+1] + bz01v[e+1] + bz11v[e+1])
                            - (bz00v[e]   + bz10v[e]   + bz01v[e]   + bz11v[e]) );

                num += c6 * ( (bx00v[e+1] + bx10v[e+1] + bx11v[e+1]) * (zcv[e+2] - zEv[e+1])
                            + (bx01v[e+1] + bx11v[e+1] + bx10v[e+1]) * (zNv[e+1] - zNEv[e+1])
                            + (by10v[e+1] + by11v[e+1] + by01v[e+1]) * (zEv[e+1] - zNEv[e+1])
                            + (by00v[e+1] + by01v[e+1] + by11v[e+1]) * (zcv[e+2] - zNv[e+1])
                            - (bx00v[e] + bx10v[e] + bx11v[e]) * (zcv[e+1] - zEv[e])
                            - (bx01v[e] + bx11v[e] + bx10v[e]) * (zNv[e] - zNEv[e])
                            - (by10v[e] + by11v[e] + by01v[e]) * (zEv[e] - zNEv[e])
                            - (by00v[e] + by01v[e] + by11v[e]) * (zcv[e+1] - zNv[e]) );

                float sbx = bx00v[e] + bx00v[e+1] + bx10v[e] + bx10v[e+1]
                          + bx01v[e] + bx01v[e+1] + bx11v[e] + bx11v[e+1];
                float sby = by00v[e] + by00v[e+1] + by10v[e] + by10v[e+1]
                          + by01v[e] + by01v[e+1] + by11v[e] + by11v[e+1];
                float sbz = bz00v[e] + bz00v[e+1] + bz10v[e] + bz10v[e+1]
                          + bz01v[e] + bz01v[e+1] + bz11v[e] + bz11v[e+1];
                float den = 0.015625f * (sbx * sbx + sby * sby + sbz * sbz) + 1e-10f;
                dv += num * num / den;
            }
        }
    }

    // ---- block reduction ----
    #pragma unroll
    for (int off = 32; off > 0; off >>= 1) {
        sm += __shfl_down(sm, off, 64);
        dv += __shfl_down(dv, off, 64);
    }

    __syncthreads();   // all LDS reads done; safe to reuse zs
    float* r1 = zs;            // 1024 floats
    float* r2 = zs + 1024;     // 1024 floats
    { float4 v; v.x = s1a[0]; v.y = s1a[1]; v.z = s1a[2]; v.w = s1a[3];
      *(float4*)&r1[tid << 2] = v; }
    { float4 v; v.x = s2a[0]; v.y = s2a[1]; v.z = s2a[2]; v.w = s2a[3];
      *(float4*)&r2[tid << 2] = v; }
    if (lane == 0) { rsc[w][0] = sm; rsc[w][1] = dv; }
    __syncthreads();

    if (tid < 64) {
        float a = 0.0f, b2 = 0.0f;
        #pragma unroll
        for (int cc = 0; cc < 16; ++cc) {
            a  += r1[cc * 64 + tid];
            b2 += r2[cc * 64 + tid];
        }
        float* sl = ws + (blockIdx.x & 31) * 258;
        if (tid < 63) {
            atomicAdd(&sl[2 + bb * 64 + tid],   a);
            atomicAdd(&sl[130 + bb * 64 + tid], b2);
        }
        if (tid == 0) atomicAdd(&sl[0], rsc[0][0] + rsc[1][0] + rsc[2][0] + rsc[3][0]);
        if (tid == 1) atomicAdd(&sl[1], rsc[0][1] + rsc[1][1] + rsc[2][1] + rsc[3][1]);
    }
}

__global__ __launch_bounds__(128) void finalize_kernel(const float* __restrict__ ws,
                                                       float* __restrict__ out)
{
    __shared__ double red[128];
    const int t = threadIdx.x;
    double stdv = 0.0;
    {
        int k = t & 63, bb = t >> 6;
        if (k < 63) {
            double s1 = 0.0, s2 = 0.0;
            for (int p = 0; p < 32; ++p) {
                s1 += (double)ws[p * 258 + 2 + bb * 64 + k];
                s2 += (double)ws[p * 258 + 130 + bb * 64 + k];
            }
            const double N = 65536.0;
            double var = (s2 - s1 * s1 / N) / (N - 1.0);
            stdv = sqrt(var > 0.0 ? var : 0.0);
        }
    }
    red[t] = stdv;
    __syncthreads();
    for (int off = 64; off > 0; off >>= 1) {
        if (t < off) red[t] += red[t + off];
        __syncthreads();
    }
    if (t == 0) {
        double smt = 0.0, dvt = 0.0;
        for (int p = 0; p < 32; ++p) {
            smt += (double)ws[p * 258 + 0];
            dvt += (double)ws[p * 258 + 1];
        }
        double loss_std    = red[0] / 126.0;
        double loss_smooth = smt / (2.0 * 254.0 * 254.0 * 61.0);
        double loss_div    = dvt / (2.0 * 255.0 * 255.0 * 63.0);
        out[0] = (float)(loss_div * 1e9);
        out[1] = (float)(loss_smooth * 10.0 + loss_std * 100.0);
    }
}

extern "C" void kernel_launch(void* const* d_in, const int* in_sizes, int n_in,
                              void* d_out, int out_size, void* d_ws, size_t ws_size,
                              hipStream_t stream) {
    const float* z  = (const float*)d_in[0];   // outputs (2,1,256,256,64)
    const float* tg = (const float*)d_in[1];   // targets (2,3,256,256,64)
    float* out = (float*)d_out;
    float* ws  = (float*)d_ws;

    zero_ws_kernel<<<1, 512, 0, stream>>>(ws);
    // 64x64 tiles x 2 batches = 8192 blocks
    fused_loss_kernel<<<8192, 256, 0, stream>>>(z, tg, ws);
    finalize_kernel<<<1, 128, 0, stream>>>(ws, out);
}